// Round 12
// baseline (222.319 us; speedup 1.0000x reference)
//
#include <hip/hip_runtime.h>
#include <math.h>

#define NE 8
#define KDIM 4096
#define PDIM 64
#define WROWS (KDIM + PDIM)   // 4160
#define EPS_F32 1.1920929e-07f
#define NCHUNK 16             // 4096 / (64 lanes * 4 floats)
#define DEPTH 4               // prefetch depth-4 => 5 register buffer sets
#define NBUF 5
#define TPW 4                 // tokens per wave
#define WAVES 8               // waves per block (512 threads)
#define ROWF4 (WROWS / 4)     // 1040 f4 per Wt row
#define LDSF4 (NE * ROWF4)    // 8320 f4 = 133120 B of LDS

typedef float f4 __attribute__((ext_vector_type(4)));

// --- tiny setup kernel: W[4160][8] -> Wt[8][4160] in d_ws ---
__global__ __launch_bounds__(256)
void transpose_w(const float* __restrict__ W, float* __restrict__ Wt) {
    const int k = blockIdx.x * 256 + threadIdx.x;
    if (k < WROWS) {
        float v[NE];
#pragma unroll
        for (int e = 0; e < NE; ++e) v[e] = W[(size_t)k * NE + e];
#pragma unroll
        for (int e = 0; e < NE; ++e) Wt[(size_t)e * WROWS + k] = v[e];
    }
}

// R11 (clean, 512-thr, 256-reg budget, LDS-Wt) + DEPTH-4 x prefetch.
// Ledger: R5 16-wave spilling ~55-60us beat R11 8-wave clean ~64us ->
// TLP/latency-hiding is the binding constraint, and R9's "kernel-internal"
// verdict was spill-confounded. R11's clean config runs 2.6 TB/s effective
// vs 27us traffic-ideal with VALU 3.4us / LDS 5us per CU -> loaded-HBM
// latency at depth-2 (8KB in flight/wave, ~600cy cover vs ~900-1500cy
// loaded latency) is the remaining candidate. Depth-4 doubles in-flight
// to 16KB/wave (128KB/CU) AND puts 4 consecutive 1KB segments of each
// token-row in flight together (same DRAM page -> better burst locality).
// Registers: xb 5*4*4=80 + acc 32 + wb 32 transient + addr ~20 = ~165,
// far under the 256-reg cap of __launch_bounds__(512,2) -- depth is
// finally affordable outside the 128-reg spill box that doomed R7.
__global__ __launch_bounds__(512, 2)
void topk_gate(const float* __restrict__ x,
               const float* __restrict__ prompt,
               const float* __restrict__ Wt,
               const float* __restrict__ b,
               float* __restrict__ out,
               int tokens)
{
    __shared__ f4 wlds[LDSF4];          // 133120 B

    const int tid  = threadIdx.x;
    const int lane = tid & 63;          // 0..63
    const int wid  = tid >> 6;          // 0..7

    const int tbase = (blockIdx.x * WAVES + wid) * TPW;
    const int phase = (blockIdx.x * 5) & 15;

    const f4* xr[TPW];
#pragma unroll
    for (int t = 0; t < TPW; ++t)
        xr[t] = (const f4*)(x + (size_t)(tbase + t) * KDIM);

    auto cidx = [&](int c) { return ((c + phase) & 15) * 64 + lane; };  // f4 units

    f4 xb[NBUF][TPW];  // depth-4 ring; indices static under full unroll

    // ---- x prologue FIRST: chunks 0..3 fly while we stage Wt -> LDS ----
#pragma unroll
    for (int c = 0; c < DEPTH; ++c) {
        const int k = cidx(c);
#pragma unroll
        for (int t = 0; t < TPW; ++t)
            xb[c][t] = __builtin_nontemporal_load(xr[t] + k);
    }

    // ---- stage Wt -> LDS (linear f4 copy, coalesced, conflict-free) ----
    {
        const f4* wt4 = (const f4*)Wt;
        for (int i = tid; i < LDSF4; i += WAVES * 64)
            wlds[i] = wt4[i];
    }
    __syncthreads();

    float acc[TPW][NE];
#pragma unroll
    for (int t = 0; t < TPW; ++t)
#pragma unroll
        for (int e = 0; e < NE; ++e) acc[t][e] = 0.f;

#pragma unroll
    for (int c = 0; c < NCHUNK; ++c) {
        if (c + DEPTH < NCHUNK) {
            const int kx = cidx(c + DEPTH);
#pragma unroll
            for (int t = 0; t < TPW; ++t)
                xb[(c + DEPTH) % NBUF][t] = __builtin_nontemporal_load(xr[t] + kx);
        }

        const int kw = cidx(c);
        f4 wb[NE];
#pragma unroll
        for (int e = 0; e < NE; ++e)
            wb[e] = wlds[e * ROWF4 + kw];

        const int s = c % NBUF;
#pragma unroll
        for (int t = 0; t < TPW; ++t)
#pragma unroll
            for (int e = 0; e < NE; ++e) {
                const f4 xv = xb[s][t];
                acc[t][e] = fmaf(xv.x, wb[e].x, acc[t][e]);
                acc[t][e] = fmaf(xv.y, wb[e].y, acc[t][e]);
                acc[t][e] = fmaf(xv.z, wb[e].z, acc[t][e]);
                acc[t][e] = fmaf(xv.w, wb[e].w, acc[t][e]);
            }
    }

    // prompt part (64 dims): lanes 0..15, w from LDS f4 cols 1024..1039
    if (lane < 16) {
        f4 pv[TPW];
#pragma unroll
        for (int t = 0; t < TPW; ++t)
            pv[t] = *((const f4*)(prompt + (size_t)(tbase + t) * PDIM) + lane);
#pragma unroll
        for (int e = 0; e < NE; ++e) {
            const f4 wv = wlds[e * ROWF4 + (KDIM / 4) + lane];
#pragma unroll
            for (int t = 0; t < TPW; ++t) {
                acc[t][e] = fmaf(pv[t].x, wv.x, acc[t][e]);
                acc[t][e] = fmaf(pv[t].y, wv.y, acc[t][e]);
                acc[t][e] = fmaf(pv[t].z, wv.z, acc[t][e]);
                acc[t][e] = fmaf(pv[t].w, wv.w, acc[t][e]);
            }
        }
    }

    // butterfly reduce: every lane ends with full logits for all 4 tokens
#pragma unroll
    for (int t = 0; t < TPW; ++t)
#pragma unroll
        for (int e = 0; e < NE; ++e) {
            float v = acc[t][e];
#pragma unroll
            for (int off = 32; off >= 1; off >>= 1)
                v += __shfl_xor(v, off, 64);
            acc[t][e] = v;
        }

    // ---- epilogue: lane = tt*16 + kk*8 + ee -> one mask element per lane ----
    const int tt = lane >> 4;
    const int kk = (lane >> 3) & 1;
    const int ee = lane & 7;

    float lg[NE];
#pragma unroll
    for (int e = 0; e < NE; ++e) {
        float v = acc[0][e];
        if (tt == 1) v = acc[1][e];
        if (tt == 2) v = acc[2][e];
        if (tt == 3) v = acc[3][e];
        lg[e] = v + b[e];
    }

    // top-2, strict > so smallest index wins ties (jax.lax.top_k semantics)
    float v0 = lg[0]; int i0 = 0;
#pragma unroll
    for (int e = 1; e < NE; ++e)
        if (lg[e] > v0) { v0 = lg[e]; i0 = e; }
    float v1 = (i0 == 0) ? lg[1] : lg[0];
    int   i1 = (i0 == 0) ? 1 : 0;
#pragma unroll
    for (int e = 0; e < NE; ++e)
        if (e != i0 && lg[e] > v1) { v1 = lg[e]; i1 = e; }

    float s = 0.f;
#pragma unroll
    for (int e = 0; e < NE; ++e) s += __expf(lg[e] - v0);
    const float g0 = 1.0f / s;
    const float g1 = __expf(v1 - v0) / s;
    const float denom = fmaxf(g0 + g1, EPS_F32);

    const int sel = kk ? i1 : i0;
    const int t_global = tbase + tt;
    out[(size_t)t_global * 16 + kk * 8 + ee] = (ee == sel) ? 1.0f : 0.0f;

    if ((lane & 15) < 2) {
        const float g = (ee == 0) ? (g0 / denom) : (g1 / denom);
        out[(size_t)tokens * 16 + (size_t)t_global * 2 + ee] = g;
    }
}

extern "C" void kernel_launch(void* const* d_in, const int* in_sizes, int n_in,
                              void* d_out, int out_size, void* d_ws, size_t ws_size,
                              hipStream_t stream) {
    const float* x      = (const float*)d_in[0];
    const float* prompt = (const float*)d_in[1];
    const float* W      = (const float*)d_in[2];
    const float* b      = (const float*)d_in[3];
    float* out          = (float*)d_out;
    float* Wt           = (float*)d_ws;          // 8*4160*4 = 133 KB

    const int tokens = in_sizes[0] / KDIM;       // 8192

    hipLaunchKernelGGL(transpose_w, dim3((WROWS + 255) / 256), dim3(256), 0, stream,
                       W, Wt);
    hipLaunchKernelGGL(topk_gate, dim3(tokens / (WAVES * TPW)), dim3(WAVES * 64),
                       0, stream, x, prompt, Wt, b, out, tokens);
}